// Round 3
// baseline (86.168 us; speedup 1.0000x reference)
//
#include <hip/hip_runtime.h>
#include <float.h>

// Chamfer distance, B=8, N1=N2=4096, 3-D fp32 points.
// dist(a,b) = |a|^2 + |b|^2 - 2 a.b ; min over the other set, both directions.
// Packed dual-FP32 inner loop: per (2 B-points x 1 A-point):
//   3 v_pk_fma_f32 + 1 v_min3_f32 = 2.0 VALU instr per pair.
// Atomic-free: each block writes partial mins for its B-chunk; reduce kernel
// min-combines 32 partials per A-point and block-atomicAdds the mean.

typedef float v2f __attribute__((ext_vector_type(2)));

#define NBATCH 8
#define NPTS   4096
#define BLK    256
#define PTS    16                 // A-points per thread; 256*16 = all 4096 A/block
#define SSPLIT 32                 // B split into 32 chunks of 128
#define BCHUNK (NPTS / SSPLIT)    // 128 B-points per block
#define PAIRS  (BCHUNK / 2)       // 64 packed pairs
#define NSLOTS (2 * NBATCH * NPTS)  // 65536 A-slots

__global__ __launch_bounds__(BLK)
void chamfer_min_kernel(const float* __restrict__ p1,
                        const float* __restrict__ p2,
                        float* __restrict__ parts /* [SSPLIT][2][8][4096] */)
{
    // Packed-pair B staging: sXY[p] = {x0,x1,y0,y1}, sZW[p] = {z0,z1,w0,w1}
    // (w = |b|^2). All lanes read the same address -> LDS broadcast.
    __shared__ float4 sXY[PAIRS];
    __shared__ float4 sZW[PAIRS];

    int bid = blockIdx.x;
    int s   = bid & (SSPLIT - 1);  bid >>= 5;
    int b   = bid & (NBATCH - 1);  bid >>= 3;
    int dir = bid;                 // 0 or 1

    const float* A    = dir ? p2 : p1;
    const float* Bpts = dir ? p1 : p2;
    int tid = threadIdx.x;

    if (tid < PAIRS) {
        const float* src = Bpts + ((size_t)b * NPTS + s * BCHUNK + 2 * tid) * 3;
        float x0 = src[0], y0 = src[1], z0 = src[2];
        float x1 = src[3], y1 = src[4], z1 = src[5];
        sXY[tid] = make_float4(x0, x1, y0, y1);
        sZW[tid] = make_float4(z0, z1,
                               x0 * x0 + y0 * y0 + z0 * z0,
                               x1 * x1 + y1 * y1 + z1 * z1);
    }

    // Per-thread A-points, pre-scaled by -2, duplicated into packed pairs.
    v2f  m2x[PTS], m2y[PTS], m2z[PTS];
    float n1[PTS], best[PTS];
#pragma unroll
    for (int k = 0; k < PTS; ++k) {
        const float* src = A + ((size_t)b * NPTS + tid + k * BLK) * 3;
        float x = src[0], y = src[1], z = src[2];
        float mx = -2.0f * x, my = -2.0f * y, mz = -2.0f * z;
        m2x[k] = (v2f){mx, mx};
        m2y[k] = (v2f){my, my};
        m2z[k] = (v2f){mz, mz};
        n1[k]  = x * x + y * y + z * z;
        best[k] = FLT_MAX;
    }
    __syncthreads();

    // Min-scan: per packed B-pair, per A-point: 3 pk_fma + 1 min3.
#pragma unroll 2
    for (int p = 0; p < PAIRS; ++p) {
        float4 xy = sXY[p];
        float4 zw = sZW[p];
        v2f qx = (v2f){xy.x, xy.y};
        v2f qy = (v2f){xy.z, xy.w};
        v2f qz = (v2f){zw.x, zw.y};
        v2f qw = (v2f){zw.z, zw.w};
#pragma unroll
        for (int k = 0; k < PTS; ++k) {
            v2f t = __builtin_elementwise_fma(m2x[k], qx, qw);
            t = __builtin_elementwise_fma(m2y[k], qy, t);
            t = __builtin_elementwise_fma(m2z[k], qz, t);
            best[k] = fminf(best[k], fminf(t.x, t.y));   // -> v_min3_f32
        }
    }

    // Coalesced partial-min stores (no atomics).
    float* dst = parts + (size_t)s * NSLOTS + ((size_t)dir * NBATCH + b) * NPTS + tid;
#pragma unroll
    for (int k = 0; k < PTS; ++k)
        dst[k * BLK] = fmaxf(best[k] + n1[k], 0.0f);
}

__global__ __launch_bounds__(BLK)
void chamfer_reduce_kernel(const float* __restrict__ parts, float* __restrict__ out)
{
    // One thread per A-slot: min over 32 partials, then sum-reduce, one
    // atomicAdd per block (256 total).
    int j = blockIdx.x * BLK + threadIdx.x;
    float m0 = FLT_MAX, m1 = FLT_MAX, m2 = FLT_MAX, m3 = FLT_MAX;
#pragma unroll
    for (int s = 0; s < SSPLIT; s += 4) {
        m0 = fminf(m0, parts[(size_t)(s + 0) * NSLOTS + j]);
        m1 = fminf(m1, parts[(size_t)(s + 1) * NSLOTS + j]);
        m2 = fminf(m2, parts[(size_t)(s + 2) * NSLOTS + j]);
        m3 = fminf(m3, parts[(size_t)(s + 3) * NSLOTS + j]);
    }
    float v = fminf(fminf(m0, m1), fminf(m2, m3));
#pragma unroll
    for (int off = 32; off > 0; off >>= 1)
        v += __shfl_down(v, off, 64);
    __shared__ float wsum[4];
    int wave = threadIdx.x >> 6;
    if ((threadIdx.x & 63) == 0) wsum[wave] = v;
    __syncthreads();
    if (threadIdx.x == 0)
        atomicAdd(out, (wsum[0] + wsum[1] + wsum[2] + wsum[3]) *
                       (1.0f / (float)(NBATCH * NPTS)));
}

extern "C" void kernel_launch(void* const* d_in, const int* in_sizes, int n_in,
                              void* d_out, int out_size, void* d_ws, size_t ws_size,
                              hipStream_t stream) {
    const float* p1 = (const float*)d_in[0];
    const float* p2 = (const float*)d_in[1];
    float* out = (float*)d_out;
    float* parts = (float*)d_ws;   // 32 * 65536 * 4 B = 8 MB

    hipMemsetAsync(d_out, 0, sizeof(float), stream);  // atomicAdd target

    int nblocks = 2 * NBATCH * SSPLIT;  // 512
    chamfer_min_kernel<<<nblocks, BLK, 0, stream>>>(p1, p2, parts);
    chamfer_reduce_kernel<<<NSLOTS / BLK, BLK, 0, stream>>>(parts, out);
}

// Round 4
// 82.766 us; speedup vs baseline: 1.0411x; 1.0411x over previous
//
#include <hip/hip_runtime.h>
#include <float.h>

// Chamfer distance, B=8, N1=N2=4096, 3-D fp32 points.
// dist(a,b) = |a|^2 + |b|^2 - 2 a.b ; min over the other set, both directions.
// Packed dual-FP32 inner loop, per (2 B-points x 1 A-point):
//   3 v_pk_fma_f32 + 1 v_min3_f32 = 2.0 VALU instr per pair.
// Cross-block combine via uint atomicMin into 256 KB L2-resident array.

typedef float v2f __attribute__((ext_vector_type(2)));

#define NBATCH 8
#define NPTS   4096
#define BLK    256
#define PTS    16                 // A-points per thread
#define NCHUNK 32
#define CHUNK  (NPTS / NCHUNK)    // 128 B-points staged per block
#define PAIRS  (CHUNK / 2)        // 64 packed pairs

__global__ __launch_bounds__(BLK)
void chamfer_min_kernel(const float* __restrict__ p1,
                        const float* __restrict__ p2,
                        unsigned int* __restrict__ mins /* [2][8][4096] uint bits */)
{
    // Packed-pair B staging: sXY[p] = {x0,x1,y0,y1}, sZW[p] = {z0,z1,w0,w1}
    // (w = |b|^2). All lanes read the same address -> LDS broadcast.
    __shared__ float4 sXY[PAIRS];
    __shared__ float4 sZW[PAIRS];

    int bid   = blockIdx.x;
    int chunk = bid & (NCHUNK - 1);  bid >>= 5;   // 32 chunks
    int b     = bid & (NBATCH - 1);  bid >>= 3;   // 8 batches
    int dir   = bid;                              // 0 or 1

    const float* A    = dir ? p2 : p1;
    const float* Bpts = dir ? p1 : p2;
    int tid = threadIdx.x;

    if (tid < PAIRS) {
        const float* s = Bpts + ((size_t)b * NPTS + chunk * CHUNK + 2 * tid) * 3;
        float x0 = s[0], y0 = s[1], z0 = s[2];
        float x1 = s[3], y1 = s[4], z1 = s[5];
        sXY[tid] = make_float4(x0, x1, y0, y1);
        sZW[tid] = make_float4(z0, z1,
                               x0 * x0 + y0 * y0 + z0 * z0,
                               x1 * x1 + y1 * y1 + z1 * z1);
    }

    // Per-thread A-points, pre-scaled by -2, duplicated into packed pairs.
    v2f  m2x[PTS], m2y[PTS], m2z[PTS];
    float n1[PTS], best[PTS];
#pragma unroll
    for (int k = 0; k < PTS; ++k) {
        const float* s = A + ((size_t)b * NPTS + tid + k * BLK) * 3;
        float x = s[0], y = s[1], z = s[2];
        float mx = -2.0f * x, my = -2.0f * y, mz = -2.0f * z;
        m2x[k] = (v2f){mx, mx};
        m2y[k] = (v2f){my, my};
        m2z[k] = (v2f){mz, mz};
        n1[k]  = x * x + y * y + z * z;
        best[k] = FLT_MAX;
    }
    __syncthreads();

    // Min-scan: per packed B-pair, per A-point: 3 pk_fma + 1 min3.
#pragma unroll 2
    for (int p = 0; p < PAIRS; ++p) {
        float4 xy = sXY[p];
        float4 zw = sZW[p];
        v2f qx = (v2f){xy.x, xy.y};
        v2f qy = (v2f){xy.z, xy.w};
        v2f qz = (v2f){zw.x, zw.y};
        v2f qw = (v2f){zw.z, zw.w};
#pragma unroll
        for (int k = 0; k < PTS; ++k) {
            v2f t = __builtin_elementwise_fma(m2x[k], qx, qw);
            t = __builtin_elementwise_fma(m2y[k], qy, t);
            t = __builtin_elementwise_fma(m2z[k], qz, t);
            best[k] = fminf(best[k], fminf(t.x, t.y));   // -> v_min3_f32
        }
    }

    // Publish per-A-point chunk-min via uint atomicMin (valid for d >= 0).
    unsigned int* marr = mins + ((size_t)dir * NBATCH + b) * NPTS + tid;
#pragma unroll
    for (int k = 0; k < PTS; ++k) {
        float d = fmaxf(best[k] + n1[k], 0.0f);
        atomicMin(&marr[k * BLK], __float_as_uint(d));
    }
}

__global__ __launch_bounds__(1024)
void chamfer_reduce_kernel(const float* __restrict__ mins, float* __restrict__ out)
{
    // Sum 2*8*4096 = 65536 min-distances; loss = sum / (8*4096).
    __shared__ float wave_sums[16];
    const float4* m4 = (const float4*)mins;
    float s = 0.0f;
#pragma unroll
    for (int i = 0; i < 16; ++i) {
        float4 v = m4[threadIdx.x + i * 1024];
        s += (v.x + v.y) + (v.z + v.w);
    }
#pragma unroll
    for (int off = 32; off > 0; off >>= 1)
        s += __shfl_down(s, off, 64);
    int wave = threadIdx.x >> 6;
    if ((threadIdx.x & 63) == 0) wave_sums[wave] = s;
    __syncthreads();
    if (threadIdx.x < 16) {
        s = wave_sums[threadIdx.x];
#pragma unroll
        for (int off = 8; off > 0; off >>= 1)
            s += __shfl_down(s, off, 16);
        if (threadIdx.x == 0) out[0] = s / (float)(NBATCH * NPTS);
    }
}

extern "C" void kernel_launch(void* const* d_in, const int* in_sizes, int n_in,
                              void* d_out, int out_size, void* d_ws, size_t ws_size,
                              hipStream_t stream) {
    const float* p1 = (const float*)d_in[0];
    const float* p2 = (const float*)d_in[1];
    float* out = (float*)d_out;
    unsigned int* mins = (unsigned int*)d_ws;

    // Init mins to 0xFFFFFFFF (uint max; > any positive float bit pattern).
    hipMemsetAsync(d_ws, 0xFF, (size_t)2 * NBATCH * NPTS * sizeof(unsigned int), stream);

    int nblocks = 2 * NBATCH * NCHUNK;  // 512
    chamfer_min_kernel<<<nblocks, BLK, 0, stream>>>(p1, p2, mins);
    chamfer_reduce_kernel<<<1, 1024, 0, stream>>>((const float*)d_ws, out);
}